// Round 10
// baseline (258.862 us; speedup 1.0000x reference)
//
#include <hip/hip_runtime.h>

#define NT 256   // 4 independent waves per block; no barriers anywhere

typedef float v2f __attribute__((ext_vector_type(2)));
typedef float f4u __attribute__((ext_vector_type(4), aligned(4)));

// Gaussian(sigma=1.5, 11 taps), normalized; 0 outside [0,10]
__device__ __forceinline__ constexpr float Wj(int j) {
    return (j < 0 || j > 10) ? 0.f :
           (j == 0 || j == 10) ? 0.00102838f :
           (j == 1 || j == 9)  ? 0.00759878f :
           (j == 2 || j == 8)  ? 0.03600077f :
           (j == 3 || j == 7)  ? 0.10936069f :
           (j == 4 || j == 6)  ? 0.21300553f : 0.26601172f;
}

// Sliding-window MS-SSIM level kernel.
// One WAVE owns 64 columns (one strip) x chunkRows output rows of one (b,c)
// image. Streams input rows top-down: per row, H-filter 4 moments
// (s=x1+x2, d=x1-x2, s^2, d^2) packed as v2f pairs, accumulate into an
// 11-slot register ring of pending V-filter outputs (static indices via
// 11-phase unroll), emit one finished output row per input row, keep
// per-lane running CS/SSIM sums. Fused 2x2 avg-pool for the next level.
// No LDS, no barriers, no per-pixel stores.
__global__ __launch_bounds__(NT, 3) void msssim_slide_kernel(
    const float* __restrict__ x1, const float* __restrict__ x2,
    float* __restrict__ p1, float* __restrict__ p2,
    float* __restrict__ accCS, float* __restrict__ accSSIM,
    int H, int W, int strips, int chunksY, int chunkRows)
{
    const int t = threadIdx.x;
    const int lane = t & 63;
    const int wid = blockIdx.x * (NT / 64) + (t >> 6);
    const int perImg = strips * chunksY;
    const int img = wid / perImg;
    const int rem = wid - img * perImg;
    const int strip = rem % strips;
    const int chunk = rem / strips;
    const int cc = strip * 64 + lane;          // my output column
    const int r0 = chunk * chunkRows;          // first output row
    const int hEnd = r0 + chunkRows + 5;       // last input row + 1
    const bool edge = (strip == 0) || (strip == strips - 1);
    const bool laneValid = (cc < W);
    const bool doPool = (p1 != nullptr);

    const size_t imgOff = (size_t)img * H * W;
    const float* __restrict__ base1 = x1 + imgOff;
    const float* __restrict__ base2 = x2 + imgOff;
    const int Wp = W >> 1;
    float* __restrict__ q1 = doPool ? (p1 + (size_t)img * ((size_t)Wp * (H >> 1))) : nullptr;
    float* __restrict__ q2 = doPool ? (p2 + (size_t)img * ((size_t)Wp * (H >> 1))) : nullptr;

    float nx1[12], nx2[12];     // current row window, cols cc-5 .. cc+6
    v2f psd[11], psq[11];       // pending V-outputs ring (assign-first lifecycle)
    float prs1 = 0.f, prs2 = 0.f;  // pool row-pair partial sums
    float cs_s = 0.f, ssim_s = 0.f;

    auto loadRow = [&](int h) {
        if (h < 0 || h >= H) return;           // virtual zero-pad rows: skip
        const float* __restrict__ r1 = base1 + (size_t)h * W;
        const float* __restrict__ r2 = base2 + (size_t)h * W;
        if (!edge) {
            const f4u* a4 = reinterpret_cast<const f4u*>(r1 + (cc - 5));
            const f4u* b4 = reinterpret_cast<const f4u*>(r2 + (cc - 5));
            f4u A0 = a4[0], A1 = a4[1], A2 = a4[2];
            f4u B0 = b4[0], B1 = b4[1], B2 = b4[2];
#pragma unroll
            for (int j = 0; j < 4; ++j) { nx1[j] = A0[j]; nx1[4 + j] = A1[j]; nx1[8 + j] = A2[j]; }
#pragma unroll
            for (int j = 0; j < 4; ++j) { nx2[j] = B0[j]; nx2[4 + j] = B1[j]; nx2[8 + j] = B2[j]; }
        } else {
            // clamped + masked scalar path (image column borders / narrow levels)
#pragma unroll
            for (int j = 0; j < 11; ++j) {
                int col = cc + j - 5;
                int cl = col < 0 ? 0 : (col > W - 1 ? W - 1 : col);
                float a = r1[cl], b = r2[cl];
                bool ok = (col >= 0) && (col < W);
                nx1[j] = ok ? a : 0.f;
                nx2[j] = ok ? b : 0.f;
            }
        }
    };

    loadRow(r0 - 5);   // prologue prefetch of first input row

    const float C1 = 0.0001f, C2 = 0.0009f;

    for (int hb = r0 - 5; hb < hEnd; hb += 11) {
#pragma unroll
        for (int p = 0; p < 11; ++p) {
            const int h = hb + p;
            if (h < hEnd) {
                // ---- 1. consume prefetched row h: H-filter 4 moments ----
                v2f acc_sd = (v2f){0.f, 0.f}, acc_sq = (v2f){0.f, 0.f};
                const bool rv = (h >= 0) && (h < H);
                if (rv) {
                    if (doPool && h >= r0 && h < r0 + chunkRows) {
                        float ra = nx1[5] + nx1[6];   // cols cc, cc+1
                        float rb = nx2[5] + nx2[6];
                        if ((h & 1) == 0) { prs1 = ra; prs2 = rb; }
                        else if (!(lane & 1) && laneValid) {
                            size_t po = (size_t)(h >> 1) * Wp + (cc >> 1);
                            q1[po] = 0.25f * (prs1 + ra);
                            q2[po] = 0.25f * (prs2 + rb);
                        }
                    }
#pragma unroll
                    for (int j = 0; j < 11; ++j) {
                        float s = nx1[j] + nx2[j];
                        float d = nx1[j] - nx2[j];
                        v2f sd = {s, d};
                        v2f w2 = {Wj(j), Wj(j)};
                        acc_sd = __builtin_elementwise_fma(w2, sd, acc_sd);
                        acc_sq = __builtin_elementwise_fma(w2, sd * sd, acc_sq);
                    }
                }
                // ---- 2. prefetch row h+1 (latency hides under step 3/4) ----
                if (h + 1 < hEnd) loadRow(h + 1);
                // ---- 3. V-ring update: row h feeds outputs h-5 .. h+5 ----
                //      output o = h+5-k gets tap W(k); k=0 assigns (fresh slot)
#pragma unroll
                for (int k = 0; k < 11; ++k) {
                    const int slot = (p + 5 - k + 11) % 11;
                    v2f w2 = {Wj(k), Wj(k)};
                    if (k == 0) {
                        psd[slot] = w2 * acc_sd;
                        psq[slot] = w2 * acc_sq;
                    } else {
                        psd[slot] = __builtin_elementwise_fma(w2, acc_sd, psd[slot]);
                        psq[slot] = __builtin_elementwise_fma(w2, acc_sq, psq[slot]);
                    }
                }
                // ---- 4. emit completed output row o = h-5 ----
                const int o = h - 5;
                if (o >= r0) {
                    const int es = (p + 6) % 11;
                    v2f m2 = psd[es] * psd[es];      // {Sm^2, Dm^2}
                    v2f t1 = psq[es] - m2;           // {SSm-Sm^2, DDm-Dm^2}
                    float num_cs = 0.5f * (t1.x - t1.y) + C2;   // 2*sigma12 + C2
                    float den_cs = 0.5f * (t1.x + t1.y) + C2;   // sig1+sig2 + C2
                    float num_ss = 0.5f * (m2.x - m2.y) + C1;   // 2*mu12 + C1
                    float den_ss = 0.5f * (m2.x + m2.y) + C1;   // mu1^2+mu2^2 + C1
                    float cs = num_cs / den_cs;
                    float ss = num_ss * cs / den_ss;
                    if (laneValid) { cs_s += cs; ssim_s += ss; }
                }
            }
        }
    }

    // ---- wave reduction -> 2 atomics per wave ----
#pragma unroll
    for (int off = 32; off > 0; off >>= 1) {
        cs_s += __shfl_down(cs_s, off);
        ssim_s += __shfl_down(ssim_s, off);
    }
    if (lane == 0) {
        atomicAdd(&accCS[img], cs_s);
        atomicAdd(&accSSIM[img], ssim_s);
    }
}

// acc layout: CS sums at acc[l*48 + img]; SSIM sums at acc[256 + l*48 + img]
__global__ void finalize_kernel(const float* __restrict__ acc, float* __restrict__ out) {
    __shared__ float vals[16];
    int t = threadIdx.x;
    if (t < 16) {
        const float w[5] = {0.0448f, 0.2856f, 0.3001f, 0.2363f, 0.1333f};
        float v = 1.f;
#pragma unroll
        for (int l = 0; l < 5; ++l) {
            int Hl = 512 >> l;
            float denom = 3.f * (float)Hl * (float)Hl;
            const float* src = (l < 4) ? (acc + l * 48) : (acc + 256 + l * 48);
            float m = src[3 * t] + src[3 * t + 1] + src[3 * t + 2];
            m = m / denom;
            m = fmaxf(m, 0.f);
            v *= powf(m, w[l]);
        }
        vals[t] = v;
    }
    __syncthreads();
    if (t == 0) {
        float s = 0.f;
        for (int i = 0; i < 16; ++i) s += vals[i];
        out[0] = s / 16.f;
    }
}

extern "C" void kernel_launch(void* const* d_in, const int* in_sizes, int n_in,
                              void* d_out, int out_size, void* d_ws, size_t ws_size,
                              hipStream_t stream) {
    const float* img1 = (const float*)d_in[0];
    const float* img2 = (const float*)d_in[1];
    float* out = (float*)d_out;
    float* ws = (float*)d_ws;

    float* acc = ws;
    size_t off = 512;
    float* x1l[5];
    float* x2l[5];
    x1l[0] = (float*)img1;
    x2l[0] = (float*)img2;
    for (int l = 1; l < 5; ++l) { int Hl = 512 >> l; x1l[l] = ws + off; off += (size_t)48 * Hl * Hl; }
    for (int l = 1; l < 5; ++l) { int Hl = 512 >> l; x2l[l] = ws + off; off += (size_t)48 * Hl * Hl; }

    hipMemsetAsync(acc, 0, 512 * sizeof(float), stream);

    for (int l = 0; l < 5; ++l) {
        int Hl = 512 >> l;
        int strips = (Hl + 63) / 64;                              // 8,4,2,1,1
        int chunkRows = (Hl >= 256) ? 64 : (Hl == 128 ? 32 : 16); // occupancy vs ramp
        int chunksY = Hl / chunkRows;
        int waves = 48 * strips * chunksY;
        int blocks = waves / (NT / 64);
        float* pp1 = (l < 4) ? x1l[l + 1] : nullptr;
        float* pp2 = (l < 4) ? x2l[l + 1] : nullptr;
        msssim_slide_kernel<<<blocks, NT, 0, stream>>>(
            x1l[l], x2l[l], pp1, pp2,
            acc + l * 48, acc + 256 + l * 48,
            Hl, Hl, strips, chunksY, chunkRows);
    }
    finalize_kernel<<<1, 64, 0, stream>>>(acc, out);
}

// Round 11
// 237.261 us; speedup vs baseline: 1.0910x; 1.0910x over previous
//
#include <hip/hip_runtime.h>

#define NT 256   // 4 independent waves per block; no barriers anywhere

typedef float v2f __attribute__((ext_vector_type(2)));
typedef float f4u __attribute__((ext_vector_type(4), aligned(4)));

// Gaussian(sigma=1.5, 11 taps), normalized; 0 outside [0,10]
__device__ __forceinline__ constexpr float Wj(int j) {
    return (j < 0 || j > 10) ? 0.f :
           (j == 0 || j == 10) ? 0.00102838f :
           (j == 1 || j == 9)  ? 0.00759878f :
           (j == 2 || j == 8)  ? 0.03600077f :
           (j == 3 || j == 7)  ? 0.10936069f :
           (j == 4 || j == 6)  ? 0.21300553f : 0.26601172f;
}

// Sliding-window MS-SSIM level kernel (see round 10). This revision:
//  - level arrays in ws are COLUMN-PADDED (stride = W+16, base offset +8,
//    zero halos written by the pool step) so levels 1..4 always take the
//    vector-load path; only level-0 border strips use the scalar clamp path.
//  - smaller row-chunks for more waves (latency hiding via TLP).
__global__ __launch_bounds__(NT, 4) void msssim_slide_kernel(
    const float* __restrict__ x1, const float* __restrict__ x2, int strideIn,
    float* __restrict__ p1, float* __restrict__ p2, int strideOut,
    float* __restrict__ accCS, float* __restrict__ accSSIM,
    int H, int W, int strips, int chunksY, int chunkRows, int padded)
{
    const int t = threadIdx.x;
    const int lane = t & 63;
    const int wid = blockIdx.x * (NT / 64) + (t >> 6);
    const int perImg = strips * chunksY;
    const int img = wid / perImg;
    const int rem = wid - img * perImg;
    const int strip = rem % strips;
    const int chunk = rem / strips;
    const int cc = strip * 64 + lane;          // my output column
    const int r0 = chunk * chunkRows;          // first output row
    const int hEnd = r0 + chunkRows + 5;       // last input row + 1
    const bool edge = (!padded) && (strip == 0 || strip == strips - 1);
    const bool laneValid = (cc < W);
    const bool doPool = (p1 != nullptr);
    const int Wp = W >> 1;

    const size_t imgIn = (size_t)img * H * strideIn;
    const float* __restrict__ base1 = x1 + imgIn;
    const float* __restrict__ base2 = x2 + imgIn;
    const size_t imgOut = doPool ? (size_t)img * (H >> 1) * strideOut : 0;
    float* __restrict__ q1 = doPool ? (p1 + imgOut) : nullptr;
    float* __restrict__ q2 = doPool ? (p2 + imgOut) : nullptr;

    float nx1[12], nx2[12];     // current row window, cols cc-5 .. cc+6
    v2f psd[11], psq[11];       // pending V-outputs ring (assign-first lifecycle)
    float prs1 = 0.f, prs2 = 0.f;  // pool row-pair partial sums
    float cs_s = 0.f, ssim_s = 0.f;

    auto loadRow = [&](int h) {
        if (h < 0 || h >= H || !laneValid) return;   // zero-pad rows / idle lanes
        const float* __restrict__ r1 = base1 + (size_t)h * strideIn;
        const float* __restrict__ r2 = base2 + (size_t)h * strideIn;
        if (!edge) {
            const f4u* a4 = reinterpret_cast<const f4u*>(r1 + (cc - 5));
            const f4u* b4 = reinterpret_cast<const f4u*>(r2 + (cc - 5));
            f4u A0 = a4[0], A1 = a4[1], A2 = a4[2];
            f4u B0 = b4[0], B1 = b4[1], B2 = b4[2];
#pragma unroll
            for (int j = 0; j < 4; ++j) { nx1[j] = A0[j]; nx1[4 + j] = A1[j]; nx1[8 + j] = A2[j]; }
#pragma unroll
            for (int j = 0; j < 4; ++j) { nx2[j] = B0[j]; nx2[4 + j] = B1[j]; nx2[8 + j] = B2[j]; }
        } else {
            // clamped + masked scalar path (level-0 image column borders)
#pragma unroll
            for (int j = 0; j < 12; ++j) {
                int col = cc + j - 5;
                int cl = col < 0 ? 0 : (col > W - 1 ? W - 1 : col);
                float a = r1[cl], b = r2[cl];
                bool ok = (col >= 0) && (col < W);
                nx1[j] = ok ? a : 0.f;
                nx2[j] = ok ? b : 0.f;
            }
        }
    };

    loadRow(r0 - 5);   // prologue prefetch of first input row

    const float C1 = 0.0001f, C2 = 0.0009f;

    for (int hb = r0 - 5; hb < hEnd; hb += 11) {
#pragma unroll
        for (int p = 0; p < 11; ++p) {
            const int h = hb + p;
            if (h < hEnd) {
                // ---- 1. consume prefetched row h: H-filter 4 moments ----
                v2f acc_sd = (v2f){0.f, 0.f}, acc_sq = (v2f){0.f, 0.f};
                const bool rv = (h >= 0) && (h < H);
                if (rv) {
                    if (doPool && h >= r0 && h < r0 + chunkRows) {
                        float ra = nx1[5] + nx1[6];   // cols cc, cc+1
                        float rb = nx2[5] + nx2[6];
                        if ((h & 1) == 0) { prs1 = ra; prs2 = rb; }
                        else if (!(lane & 1) && laneValid) {
                            size_t po = (size_t)(h >> 1) * strideOut + (cc >> 1);
                            q1[po] = 0.25f * (prs1 + ra);
                            q2[po] = 0.25f * (prs2 + rb);
                            // zero halos of the padded next-level image
                            if (cc == 0) {
                                *(f4u*)&q1[po - 8] = (f4u){0.f, 0.f, 0.f, 0.f};
                                *(f4u*)&q1[po - 4] = (f4u){0.f, 0.f, 0.f, 0.f};
                                *(f4u*)&q2[po - 8] = (f4u){0.f, 0.f, 0.f, 0.f};
                                *(f4u*)&q2[po - 4] = (f4u){0.f, 0.f, 0.f, 0.f};
                            }
                            if ((cc >> 1) == Wp - 1) {
#pragma unroll
                                for (int j = 1; j <= 8; ++j) { q1[po + j] = 0.f; q2[po + j] = 0.f; }
                            }
                        }
                    }
#pragma unroll
                    for (int j = 0; j < 11; ++j) {
                        float s = nx1[j] + nx2[j];
                        float d = nx1[j] - nx2[j];
                        v2f sd = {s, d};
                        v2f w2 = {Wj(j), Wj(j)};
                        acc_sd = __builtin_elementwise_fma(w2, sd, acc_sd);
                        acc_sq = __builtin_elementwise_fma(w2, sd * sd, acc_sq);
                    }
                }
                // ---- 2. prefetch row h+1 (latency hides under step 3/4) ----
                if (h + 1 < hEnd) loadRow(h + 1);
                // ---- 3. V-ring update: row h feeds outputs h-5 .. h+5 ----
#pragma unroll
                for (int k = 0; k < 11; ++k) {
                    const int slot = (p + 5 - k + 11) % 11;
                    v2f w2 = {Wj(k), Wj(k)};
                    if (k == 0) {
                        psd[slot] = w2 * acc_sd;
                        psq[slot] = w2 * acc_sq;
                    } else {
                        psd[slot] = __builtin_elementwise_fma(w2, acc_sd, psd[slot]);
                        psq[slot] = __builtin_elementwise_fma(w2, acc_sq, psq[slot]);
                    }
                }
                // ---- 4. emit completed output row o = h-5 ----
                const int o = h - 5;
                if (o >= r0) {
                    const int es = (p + 6) % 11;
                    v2f m2 = psd[es] * psd[es];      // {Sm^2, Dm^2}
                    v2f t1 = psq[es] - m2;           // {SSm-Sm^2, DDm-Dm^2}
                    float num_cs = 0.5f * (t1.x - t1.y) + C2;   // 2*sigma12 + C2
                    float den_cs = 0.5f * (t1.x + t1.y) + C2;   // sig1+sig2 + C2
                    float num_ss = 0.5f * (m2.x - m2.y) + C1;   // 2*mu12 + C1
                    float den_ss = 0.5f * (m2.x + m2.y) + C1;   // mu1^2+mu2^2 + C1
                    float cs = num_cs / den_cs;
                    float ss = num_ss * cs / den_ss;
                    if (laneValid) { cs_s += cs; ssim_s += ss; }
                }
            }
        }
    }

    // ---- wave reduction -> 2 atomics per wave ----
#pragma unroll
    for (int off = 32; off > 0; off >>= 1) {
        cs_s += __shfl_down(cs_s, off);
        ssim_s += __shfl_down(ssim_s, off);
    }
    if (lane == 0) {
        atomicAdd(&accCS[img], cs_s);
        atomicAdd(&accSSIM[img], ssim_s);
    }
}

// acc layout: CS sums at acc[l*48 + img]; SSIM sums at acc[256 + l*48 + img]
__global__ void finalize_kernel(const float* __restrict__ acc, float* __restrict__ out) {
    __shared__ float vals[16];
    int t = threadIdx.x;
    if (t < 16) {
        const float w[5] = {0.0448f, 0.2856f, 0.3001f, 0.2363f, 0.1333f};
        float v = 1.f;
#pragma unroll
        for (int l = 0; l < 5; ++l) {
            int Hl = 512 >> l;
            float denom = 3.f * (float)Hl * (float)Hl;
            const float* src = (l < 4) ? (acc + l * 48) : (acc + 256 + l * 48);
            float m = src[3 * t] + src[3 * t + 1] + src[3 * t + 2];
            m = m / denom;
            m = fmaxf(m, 0.f);
            v *= powf(m, w[l]);
        }
        vals[t] = v;
    }
    __syncthreads();
    if (t == 0) {
        float s = 0.f;
        for (int i = 0; i < 16; ++i) s += vals[i];
        out[0] = s / 16.f;
    }
}

extern "C" void kernel_launch(void* const* d_in, const int* in_sizes, int n_in,
                              void* d_out, int out_size, void* d_ws, size_t ws_size,
                              hipStream_t stream) {
    const float* img1 = (const float*)d_in[0];
    const float* img2 = (const float*)d_in[1];
    float* out = (float*)d_out;
    float* ws = (float*)d_ws;

    float* acc = ws;
    size_t off = 512;

    // level arrays: padded stride Wl+16, pointer offset +8 (column halo)
    float* a1[5];
    float* a2[5];
    int strideL[5];
    a1[0] = (float*)img1; a2[0] = (float*)img2; strideL[0] = 512;
    for (int l = 1; l < 5; ++l) {
        int Hl = 512 >> l;
        strideL[l] = Hl + 16;
        a1[l] = ws + off + 8; off += (size_t)48 * Hl * strideL[l];
    }
    for (int l = 1; l < 5; ++l) {
        int Hl = 512 >> l;
        a2[l] = ws + off + 8; off += (size_t)48 * Hl * strideL[l];
    }

    hipMemsetAsync(acc, 0, 512 * sizeof(float), stream);

    for (int l = 0; l < 5; ++l) {
        int Hl = 512 >> l;
        int strips = (Hl + 63) / 64;                    // 8,4,2,1,1
        int chunkRows = (l == 0) ? 32 : 16;
        int chunksY = Hl / chunkRows;
        int waves = 48 * strips * chunksY;
        int blocks = waves / (NT / 64);
        float* pp1 = (l < 4) ? a1[l + 1] : nullptr;
        float* pp2 = (l < 4) ? a2[l + 1] : nullptr;
        int so = (l < 4) ? strideL[l + 1] : 0;
        msssim_slide_kernel<<<blocks, NT, 0, stream>>>(
            a1[l], a2[l], strideL[l], pp1, pp2, so,
            acc + l * 48, acc + 256 + l * 48,
            Hl, Hl, strips, chunksY, chunkRows, l > 0 ? 1 : 0);
    }
    finalize_kernel<<<1, 64, 0, stream>>>(acc, out);
}

// Round 12
// 199.438 us; speedup vs baseline: 1.2980x; 1.1896x over previous
//
#include <hip/hip_runtime.h>

#define NT 256   // 4 independent waves per block; no barriers anywhere

typedef float v2f __attribute__((ext_vector_type(2)));
typedef float f4u __attribute__((ext_vector_type(4), aligned(4)));

// Gaussian(sigma=1.5, 11 taps), normalized; 0 outside [0,10]
__device__ __forceinline__ constexpr float Wj(int j) {
    return (j < 0 || j > 10) ? 0.f :
           (j == 0 || j == 10) ? 0.00102838f :
           (j == 1 || j == 9)  ? 0.00759878f :
           (j == 2 || j == 8)  ? 0.03600077f :
           (j == 3 || j == 7)  ? 0.10936069f :
           (j == 4 || j == 6)  ? 0.21300553f : 0.26601172f;
}

// Sliding-window MS-SSIM level kernel (round 10 structure). This revision:
//  - amdgpu_waves_per_eu(2,4): stop the regalloc from chasing 8 waves/SIMD
//    with a 64-VGPR budget (live state is ~85 regs: 44 ring + 24 window);
//    let it allocate ~96-128 and keep the V-ring + prefetch in registers.
//  - sched_barrier(0) pins the next-row prefetch issue point.
//  - XCD-aware bijective swizzle (r9-proven): 6 whole images per XCD,
//    vertical-first order within an image for chunk-halo L2 reuse.
__global__ __attribute__((amdgpu_flat_work_group_size(NT, NT), amdgpu_waves_per_eu(2, 4)))
void msssim_slide_kernel(
    const float* __restrict__ x1, const float* __restrict__ x2, int strideIn,
    float* __restrict__ p1, float* __restrict__ p2, int strideOut,
    float* __restrict__ accCS, float* __restrict__ accSSIM,
    int H, int W, int strips, int chunksY, int chunkRows, int padded)
{
    const int t = threadIdx.x;
    const int lane = t & 63;

    // ---- bijective XCD swizzle (gridDim.x always a multiple of 8) ----
    const int cpx = gridDim.x >> 3;
    const int lb = (blockIdx.x & 7) * cpx + (blockIdx.x >> 3);
    const int wid = lb * (NT / 64) + (t >> 6);

    const int perImg = strips * chunksY;
    const int img = wid / perImg;
    const int rem = wid - img * perImg;
    const int strip = rem / chunksY;           // vertical-first within image
    const int chunk = rem % chunksY;
    const int cc = strip * 64 + lane;          // my output column
    const int r0 = chunk * chunkRows;          // first output row
    const int hEnd = r0 + chunkRows + 5;       // last input row + 1
    const bool edge = (!padded) && (strip == 0 || strip == strips - 1);
    const bool laneValid = (cc < W);
    const bool doPool = (p1 != nullptr);
    const int Wp = W >> 1;

    const size_t imgIn = (size_t)img * H * strideIn;
    const float* __restrict__ base1 = x1 + imgIn;
    const float* __restrict__ base2 = x2 + imgIn;
    const size_t imgOut = doPool ? (size_t)img * (H >> 1) * strideOut : 0;
    float* __restrict__ q1 = doPool ? (p1 + imgOut) : nullptr;
    float* __restrict__ q2 = doPool ? (p2 + imgOut) : nullptr;

    float nx1[12], nx2[12];     // current row window, cols cc-5 .. cc+6
    v2f psd[11], psq[11];       // pending V-outputs ring (assign-first lifecycle)
    float prs1 = 0.f, prs2 = 0.f;  // pool row-pair partial sums
    float cs_s = 0.f, ssim_s = 0.f;

    auto loadRow = [&](int h) {
        if (h < 0 || h >= H || !laneValid) return;   // zero-pad rows / idle lanes
        const float* __restrict__ r1 = base1 + (size_t)h * strideIn;
        const float* __restrict__ r2 = base2 + (size_t)h * strideIn;
        if (!edge) {
            const f4u* a4 = reinterpret_cast<const f4u*>(r1 + (cc - 5));
            const f4u* b4 = reinterpret_cast<const f4u*>(r2 + (cc - 5));
            f4u A0 = a4[0], A1 = a4[1], A2 = a4[2];
            f4u B0 = b4[0], B1 = b4[1], B2 = b4[2];
#pragma unroll
            for (int j = 0; j < 4; ++j) { nx1[j] = A0[j]; nx1[4 + j] = A1[j]; nx1[8 + j] = A2[j]; }
#pragma unroll
            for (int j = 0; j < 4; ++j) { nx2[j] = B0[j]; nx2[4 + j] = B1[j]; nx2[8 + j] = B2[j]; }
        } else {
            // clamped + masked scalar path (level-0 image column borders)
#pragma unroll
            for (int j = 0; j < 12; ++j) {
                int col = cc + j - 5;
                int cl = col < 0 ? 0 : (col > W - 1 ? W - 1 : col);
                float a = r1[cl], b = r2[cl];
                bool ok = (col >= 0) && (col < W);
                nx1[j] = ok ? a : 0.f;
                nx2[j] = ok ? b : 0.f;
            }
        }
    };

    loadRow(r0 - 5);   // prologue prefetch of first input row

    const float C1 = 0.0001f, C2 = 0.0009f;

    for (int hb = r0 - 5; hb < hEnd; hb += 11) {
#pragma unroll
        for (int p = 0; p < 11; ++p) {
            const int h = hb + p;
            if (h < hEnd) {
                // ---- 1. consume prefetched row h: H-filter 4 moments ----
                v2f acc_sd = (v2f){0.f, 0.f}, acc_sq = (v2f){0.f, 0.f};
                const bool rv = (h >= 0) && (h < H);
                if (rv) {
                    if (doPool && h >= r0 && h < r0 + chunkRows) {
                        float ra = nx1[5] + nx1[6];   // cols cc, cc+1
                        float rb = nx2[5] + nx2[6];
                        if ((h & 1) == 0) { prs1 = ra; prs2 = rb; }
                        else if (!(lane & 1) && laneValid) {
                            size_t po = (size_t)(h >> 1) * strideOut + (cc >> 1);
                            q1[po] = 0.25f * (prs1 + ra);
                            q2[po] = 0.25f * (prs2 + rb);
                            // zero halos of the padded next-level image
                            if (cc == 0) {
                                *(f4u*)&q1[po - 8] = (f4u){0.f, 0.f, 0.f, 0.f};
                                *(f4u*)&q1[po - 4] = (f4u){0.f, 0.f, 0.f, 0.f};
                                *(f4u*)&q2[po - 8] = (f4u){0.f, 0.f, 0.f, 0.f};
                                *(f4u*)&q2[po - 4] = (f4u){0.f, 0.f, 0.f, 0.f};
                            }
                            if ((cc >> 1) == Wp - 1) {
#pragma unroll
                                for (int j = 1; j <= 8; ++j) { q1[po + j] = 0.f; q2[po + j] = 0.f; }
                            }
                        }
                    }
#pragma unroll
                    for (int j = 0; j < 11; ++j) {
                        float s = nx1[j] + nx2[j];
                        float d = nx1[j] - nx2[j];
                        v2f sd = {s, d};
                        v2f w2 = {Wj(j), Wj(j)};
                        acc_sd = __builtin_elementwise_fma(w2, sd, acc_sd);
                        acc_sq = __builtin_elementwise_fma(w2, sd * sd, acc_sq);
                    }
                }
                // ---- 2. prefetch row h+1; pin the issue point ----
                if (h + 1 < hEnd) loadRow(h + 1);
                __builtin_amdgcn_sched_barrier(0);
                // ---- 3. V-ring update: row h feeds outputs h-5 .. h+5 ----
#pragma unroll
                for (int k = 0; k < 11; ++k) {
                    const int slot = (p + 5 - k + 11) % 11;
                    v2f w2 = {Wj(k), Wj(k)};
                    if (k == 0) {
                        psd[slot] = w2 * acc_sd;
                        psq[slot] = w2 * acc_sq;
                    } else {
                        psd[slot] = __builtin_elementwise_fma(w2, acc_sd, psd[slot]);
                        psq[slot] = __builtin_elementwise_fma(w2, acc_sq, psq[slot]);
                    }
                }
                // ---- 4. emit completed output row o = h-5 ----
                const int o = h - 5;
                if (o >= r0) {
                    const int es = (p + 6) % 11;
                    v2f m2 = psd[es] * psd[es];      // {Sm^2, Dm^2}
                    v2f t1 = psq[es] - m2;           // {SSm-Sm^2, DDm-Dm^2}
                    float num_cs = 0.5f * (t1.x - t1.y) + C2;   // 2*sigma12 + C2
                    float den_cs = 0.5f * (t1.x + t1.y) + C2;   // sig1+sig2 + C2
                    float num_ss = 0.5f * (m2.x - m2.y) + C1;   // 2*mu12 + C1
                    float den_ss = 0.5f * (m2.x + m2.y) + C1;   // mu1^2+mu2^2 + C1
                    float cs = num_cs / den_cs;
                    float ss = num_ss * cs / den_ss;
                    if (laneValid) { cs_s += cs; ssim_s += ss; }
                }
            }
        }
    }

    // ---- wave reduction -> 2 atomics per wave ----
#pragma unroll
    for (int off = 32; off > 0; off >>= 1) {
        cs_s += __shfl_down(cs_s, off);
        ssim_s += __shfl_down(ssim_s, off);
    }
    if (lane == 0) {
        atomicAdd(&accCS[img], cs_s);
        atomicAdd(&accSSIM[img], ssim_s);
    }
}

// acc layout: CS sums at acc[l*48 + img]; SSIM sums at acc[256 + l*48 + img]
__global__ void finalize_kernel(const float* __restrict__ acc, float* __restrict__ out) {
    __shared__ float vals[16];
    int t = threadIdx.x;
    if (t < 16) {
        const float w[5] = {0.0448f, 0.2856f, 0.3001f, 0.2363f, 0.1333f};
        float v = 1.f;
#pragma unroll
        for (int l = 0; l < 5; ++l) {
            int Hl = 512 >> l;
            float denom = 3.f * (float)Hl * (float)Hl;
            const float* src = (l < 4) ? (acc + l * 48) : (acc + 256 + l * 48);
            float m = src[3 * t] + src[3 * t + 1] + src[3 * t + 2];
            m = m / denom;
            m = fmaxf(m, 0.f);
            v *= powf(m, w[l]);
        }
        vals[t] = v;
    }
    __syncthreads();
    if (t == 0) {
        float s = 0.f;
        for (int i = 0; i < 16; ++i) s += vals[i];
        out[0] = s / 16.f;
    }
}

extern "C" void kernel_launch(void* const* d_in, const int* in_sizes, int n_in,
                              void* d_out, int out_size, void* d_ws, size_t ws_size,
                              hipStream_t stream) {
    const float* img1 = (const float*)d_in[0];
    const float* img2 = (const float*)d_in[1];
    float* out = (float*)d_out;
    float* ws = (float*)d_ws;

    float* acc = ws;
    size_t off = 512;

    // level arrays: padded stride Wl+16, pointer offset +8 (column halo)
    float* a1[5];
    float* a2[5];
    int strideL[5];
    a1[0] = (float*)img1; a2[0] = (float*)img2; strideL[0] = 512;
    for (int l = 1; l < 5; ++l) {
        int Hl = 512 >> l;
        strideL[l] = Hl + 16;
        a1[l] = ws + off + 8; off += (size_t)48 * Hl * strideL[l];
    }
    for (int l = 1; l < 5; ++l) {
        int Hl = 512 >> l;
        a2[l] = ws + off + 8; off += (size_t)48 * Hl * strideL[l];
    }

    hipMemsetAsync(acc, 0, 512 * sizeof(float), stream);

    for (int l = 0; l < 5; ++l) {
        int Hl = 512 >> l;
        int strips = (Hl + 63) / 64;                    // 8,4,2,1,1
        int chunkRows = (l == 0) ? 64 : (l == 1 ? 16 : 8);
        int chunksY = Hl / chunkRows;
        int waves = 48 * strips * chunksY;
        int blocks = waves / (NT / 64);                 // always % 8 == 0
        float* pp1 = (l < 4) ? a1[l + 1] : nullptr;
        float* pp2 = (l < 4) ? a2[l + 1] : nullptr;
        int so = (l < 4) ? strideL[l + 1] : 0;
        msssim_slide_kernel<<<blocks, NT, 0, stream>>>(
            a1[l], a2[l], strideL[l], pp1, pp2, so,
            acc + l * 48, acc + 256 + l * 48,
            Hl, Hl, strips, chunksY, chunkRows, l > 0 ? 1 : 0);
    }
    finalize_kernel<<<1, 64, 0, stream>>>(acc, out);
}